// Round 1
// baseline (2177.270 us; speedup 1.0000x reference)
//
#include <hip/hip_runtime.h>
#include <stdint.h>

// JAX >= 0.4.36 defaults jax_threefry_partitionable=True. If this round fails
// with absmax ~1.0, flip to 0 (legacy iota-halves threefry semantics).
#define PARTITIONABLE 1

constexpr int NN = 10000;          // nodes
constexpr int EE = 1000;           // hyperedges
constexpr int TT = 30;             // output rows
constexpr int TS = TT - 1;         // simulated steps
constexpr int ROW = NN * 3;        // 30000 floats per output row
constexpr int S_OFF = TT * ROW;    // state section offset in d_out
constexpr int CAP_E = 48;          // max nodes per edge (Binom(10000,0.001): P(>=48) ~ 1e-30)
constexpr int CAP_N = 16;          // max edges per node (Binom(1000,0.001):  P(>=16) ~ 1e-14)

// ---- Threefry-2x32, 20 rounds (exact JAX semantics), host+device ----
__host__ __device__ inline void tf2x32(uint32_t k0, uint32_t k1,
                                       uint32_t x0, uint32_t x1,
                                       uint32_t &o0, uint32_t &o1) {
  uint32_t ks2 = k0 ^ k1 ^ 0x1BD11BDAu;
  x0 += k0; x1 += k1;
#define TFR(r) do { x0 += x1; x1 = (x1 << (r)) | (x1 >> (32 - (r))); x1 ^= x0; } while (0)
  TFR(13); TFR(15); TFR(26); TFR(6);
  x0 += k1;  x1 += ks2 + 1u;
  TFR(17); TFR(29); TFR(16); TFR(24);
  x0 += ks2; x1 += k0 + 2u;
  TFR(13); TFR(15); TFR(26); TFR(6);
  x0 += k0;  x1 += k1 + 3u;
  TFR(17); TFR(29); TFR(16); TFR(24);
  x0 += k1;  x1 += ks2 + 4u;
  TFR(13); TFR(15); TFR(26); TFR(6);
  x0 += ks2; x1 += k0 + 5u;
#undef TFR
  o0 = x0; o1 = x1;
}

__device__ inline float bits_to_uniform(uint32_t bits) {
  // jax: bitcast((bits>>9)|0x3F800000) - 1.0, then *1.0+0.0, then max(0, .)
  float f = __uint_as_float((bits >> 9) | 0x3F800000u) - 1.0f;
  return f < 0.f ? 0.f : f;
}

// Shared SIR update tail; exact rounding order as reference (no FMA contraction).
__device__ inline void sir_update(int n, float nv,
                                  const float* __restrict__ pp, const float* __restrict__ sp,
                                  float* __restrict__ po, float* __restrict__ so,
                                  const float* __restrict__ beta, const float* __restrict__ gamma_,
                                  uint32_t k1a, uint32_t k1b, uint32_t k2a, uint32_t k2b) {
  float s0 = sp[n * 3 + 0], s1 = sp[n * 3 + 1];
  float pp0 = pp[n * 3 + 0], pp1 = pp[n * 3 + 1], pp2 = pp[n * 3 + 2];
  float new_cases = __fmul_rn(beta[n], nv);
  float new_rec   = __fmul_rn(gamma_[n], s1);
  float p0 = fminf(1.f, fmaxf(0.f, __fsub_rn(pp0, new_cases)));
  float p1 = fminf(1.f, fmaxf(0.f, __fsub_rn(__fadd_rn(pp1, new_cases), new_rec)));
  float p2 = fminf(1.f, fmaxf(0.f, __fadd_rn(pp2, new_rec)));

  uint32_t a, b, bits1, bits2;
#if PARTITIONABLE
  tf2x32(k1a, k1b, 0u, (uint32_t)n, a, b); bits1 = a ^ b;
  tf2x32(k2a, k2b, 0u, (uint32_t)n, a, b); bits2 = a ^ b;
#else
  uint32_t j = (n < NN / 2) ? (uint32_t)n : (uint32_t)(n - NN / 2);
  tf2x32(k1a, k1b, j, j + NN / 2, a, b); bits1 = (n < NN / 2) ? a : b;
  tf2x32(k2a, k2b, j, j + NN / 2, a, b); bits2 = (n < NN / 2) ? a : b;
#endif
  float u1 = bits_to_uniform(bits1);
  float u2 = bits_to_uniform(bits2);

  bool was_S  = (s0 == 1.f);
  bool was_I  = (s1 == 1.f);
  bool s_to_I = was_S && (u1 < p1);
  bool i_event = was_I && (u1 < p2);
  bool u2lt   = (u2 < 0.5f);
  bool i_to_R = i_event && u2lt;
  bool i_to_S = i_event && !u2lt;
  bool new_S = (was_S && !s_to_I) || i_to_S;
  bool new_I = s_to_I || (was_I && !i_event);
  bool new_R = (!was_S && !was_I) || i_to_R;

  po[n * 3 + 0] = p0; po[n * 3 + 1] = p1; po[n * 3 + 2] = p2;
  so[n * 3 + 0] = new_S ? 1.f : 0.f;
  so[n * 3 + 1] = new_I ? 1.f : 0.f;
  so[n * 3 + 2] = new_R ? 1.f : 0.f;
}

// ---- preprocessing: edge->node lists for all (t,e) rows; zeroes node_cnt ----
__global__ void k_scan(const float* __restrict__ H, int* __restrict__ edge_cnt,
                       uint16_t* __restrict__ edge_nodes, int* __restrict__ node_cnt) {
  const int row = blockIdx.x;  // t*EE + e
  __shared__ int cnt;
  __shared__ uint16_t list[CAP_E];
  if (threadIdx.x == 0) cnt = 0;
  if (threadIdx.x < 10) node_cnt[row * 10 + threadIdx.x] = 0;  // EE*10 == NN: exact cover
  __syncthreads();
  const float4* hrow = reinterpret_cast<const float4*>(H + (size_t)row * NN);
  for (int i = threadIdx.x; i < NN / 4; i += blockDim.x) {
    float4 v = hrow[i];
    int b4 = i * 4;
    if (v.x != 0.f) { int p = atomicAdd(&cnt, 1); if (p < CAP_E) list[p] = (uint16_t)(b4 + 0); }
    if (v.y != 0.f) { int p = atomicAdd(&cnt, 1); if (p < CAP_E) list[p] = (uint16_t)(b4 + 1); }
    if (v.z != 0.f) { int p = atomicAdd(&cnt, 1); if (p < CAP_E) list[p] = (uint16_t)(b4 + 2); }
    if (v.w != 0.f) { int p = atomicAdd(&cnt, 1); if (p < CAP_E) list[p] = (uint16_t)(b4 + 3); }
  }
  __syncthreads();
  int c = cnt < CAP_E ? cnt : CAP_E;
  if (threadIdx.x == 0) edge_cnt[row] = c;
  if ((int)threadIdx.x < c) edge_nodes[(size_t)row * CAP_E + threadIdx.x] = list[threadIdx.x];
}

// ---- preprocessing: transpose into node->edge lists via atomics ----
__global__ void k_scatter(const int* __restrict__ edge_cnt, const uint16_t* __restrict__ edge_nodes,
                          int* __restrict__ node_cnt, uint16_t* __restrict__ node_edges) {
  const int row = blockIdx.x;  // t*EE + e
  const int t = row / EE;
  const int e = row - t * EE;
  const int c = edge_cnt[row];
  for (int i = threadIdx.x; i < c; i += blockDim.x) {
    int m = edge_nodes[(size_t)row * CAP_E + i];
    int slot = atomicAdd(&node_cnt[t * NN + m], 1);
    if (slot < CAP_N) node_edges[((size_t)t * NN + m) * CAP_N + slot] = (uint16_t)e;
  }
}

__global__ void k_init(const float* __restrict__ x, float* __restrict__ out) {
  int i = blockIdx.x * blockDim.x + threadIdx.x;
  if (i < ROW) { out[i] = x[i]; out[S_OFF + i] = x[i]; }
}

// ---- one simulation step, sparse two-hop gather ----
__global__ void k_step_sparse(float* __restrict__ out,
                              const int* __restrict__ edge_cnt, const uint16_t* __restrict__ edge_nodes,
                              const int* __restrict__ node_cnt, const uint16_t* __restrict__ node_edges,
                              const float* __restrict__ beta, const float* __restrict__ gamma_,
                              int t, uint32_t k1a, uint32_t k1b, uint32_t k2a, uint32_t k2b) {
  int n = blockIdx.x * blockDim.x + threadIdx.x;
  if (n >= NN) return;
  const float* pp = out + (size_t)t * ROW;
  const float* sp = out + S_OFF + (size_t)t * ROW;
  float* po = out + (size_t)(t + 1) * ROW;
  float* so = out + S_OFF + (size_t)(t + 1) * ROW;

  // node_val[n] = sum_{e in edges(n)} sum_{m in nodes(e)} infected[m]  (exact small ints)
  float nv = 0.f;
  int nc = node_cnt[t * NN + n]; if (nc > CAP_N) nc = CAP_N;
  const uint16_t* nlst = node_edges + ((size_t)t * NN + n) * CAP_N;
  for (int k = 0; k < nc; ++k) {
    int e = nlst[k];
    int row = t * EE + e;
    int ec = edge_cnt[row];
    const uint16_t* elst = edge_nodes + (size_t)row * CAP_E;
    float ei = 0.f;
    for (int m = 0; m < ec; ++m) ei += sp[elst[m] * 3 + 1];
    nv += ei;
  }
  sir_update(n, nv, pp, sp, po, so, beta, gamma_, k1a, k1b, k2a, k2b);
}

// ---- dense fallback (used only if ws_size too small for sparse rep) ----
__global__ void k_edge_dense(const float* __restrict__ Ht, const float* __restrict__ sp,
                             float* __restrict__ e_inf) {
  __shared__ float red[256];
  const float4* row = reinterpret_cast<const float4*>(Ht + (size_t)blockIdx.x * NN);
  float acc = 0.f;
  for (int i = threadIdx.x; i < NN / 4; i += blockDim.x) {
    float4 v = row[i];
    int b4 = i * 4;
    if (v.x != 0.f) acc += sp[(b4 + 0) * 3 + 1];
    if (v.y != 0.f) acc += sp[(b4 + 1) * 3 + 1];
    if (v.z != 0.f) acc += sp[(b4 + 2) * 3 + 1];
    if (v.w != 0.f) acc += sp[(b4 + 3) * 3 + 1];
  }
  red[threadIdx.x] = acc;
  __syncthreads();
  for (int s = 128; s > 0; s >>= 1) {
    if ((int)threadIdx.x < s) red[threadIdx.x] += red[threadIdx.x + s];
    __syncthreads();
  }
  if (threadIdx.x == 0) e_inf[blockIdx.x] = red[0];
}

__global__ void k_node_dense(float* __restrict__ out, const float* __restrict__ Ht,
                             const float* __restrict__ e_inf,
                             const float* __restrict__ beta, const float* __restrict__ gamma_,
                             int t, uint32_t k1a, uint32_t k1b, uint32_t k2a, uint32_t k2b) {
  __shared__ float ei[EE];
  for (int i = threadIdx.x; i < EE; i += blockDim.x) ei[i] = e_inf[i];
  __syncthreads();
  int n = blockIdx.x * blockDim.x + threadIdx.x;
  if (n >= NN) return;
  const float* pp = out + (size_t)t * ROW;
  const float* sp = out + S_OFF + (size_t)t * ROW;
  float* po = out + (size_t)(t + 1) * ROW;
  float* so = out + S_OFF + (size_t)(t + 1) * ROW;
  float nv = 0.f;
  for (int e = 0; e < EE; ++e) {
    float h = Ht[(size_t)e * NN + n];
    if (h != 0.f) nv += ei[e];
  }
  sir_update(n, nv, pp, sp, po, so, beta, gamma_, k1a, k1b, k2a, k2b);
}

extern "C" void kernel_launch(void* const* d_in, const int* in_sizes, int n_in,
                              void* d_out, int out_size, void* d_ws, size_t ws_size,
                              hipStream_t stream) {
  const float* x      = (const float*)d_in[0];
  const float* H      = (const float*)d_in[1];
  const float* beta   = (const float*)d_in[2];
  const float* gamma_ = (const float*)d_in[3];
  float* out = (float*)d_out;

  // Host-side key chain: key0 = jax.random.key(42) = (0,42); per step split(key,3).
  uint32_t K1A[TS], K1B[TS], K2A[TS], K2B[TS];
  uint32_t key0 = 0u, key1 = 42u;
  for (int t = 0; t < TS; ++t) {
    uint32_t a0, b0, a1, b1, a2, b2;
#if PARTITIONABLE
    tf2x32(key0, key1, 0u, 0u, a0, b0);   // new carry key
    tf2x32(key0, key1, 0u, 1u, a1, b1);   // k1
    tf2x32(key0, key1, 0u, 2u, a2, b2);   // k2
    K1A[t] = a1; K1B[t] = b1; K2A[t] = a2; K2B[t] = b2;
    key0 = a0; key1 = b0;
#else
    // legacy: counts iota(6) split into halves -> pairs (i, i+3)
    tf2x32(key0, key1, 0u, 3u, a0, b0);
    tf2x32(key0, key1, 1u, 4u, a1, b1);
    tf2x32(key0, key1, 2u, 5u, a2, b2);
    // flat [a0,a1,a2,b0,b1,b2] reshaped (3,2): key=(a0,a1) k1=(a2,b0) k2=(b1,b2)
    K1A[t] = a2; K1B[t] = b0; K2A[t] = b1; K2B[t] = b2;
    key0 = a0; key1 = a1;
#endif
  }

  // workspace layout
  size_t off = 0;
  auto take = [&](size_t bytes) { size_t o = off; off += (bytes + 255) & ~(size_t)255; return o; };
  size_t o_ec = take((size_t)TS * EE * sizeof(int));
  size_t o_en = take((size_t)TS * EE * CAP_E * sizeof(uint16_t));
  size_t o_nc = take((size_t)TS * NN * sizeof(int));
  size_t o_ne = take((size_t)TS * NN * CAP_N * sizeof(uint16_t));
  bool use_sparse = (ws_size >= off);

  k_init<<<(ROW + 255) / 256, 256, 0, stream>>>(x, out);

  if (use_sparse) {
    int*      edge_cnt   = (int*)((char*)d_ws + o_ec);
    uint16_t* edge_nodes = (uint16_t*)((char*)d_ws + o_en);
    int*      node_cnt   = (int*)((char*)d_ws + o_nc);
    uint16_t* node_edges = (uint16_t*)((char*)d_ws + o_ne);
    k_scan<<<TS * EE, 256, 0, stream>>>(H, edge_cnt, edge_nodes, node_cnt);
    k_scatter<<<TS * EE, 64, 0, stream>>>(edge_cnt, edge_nodes, node_cnt, node_edges);
    for (int t = 0; t < TS; ++t) {
      k_step_sparse<<<(NN + 255) / 256, 256, 0, stream>>>(
          out, edge_cnt, edge_nodes, node_cnt, node_edges, beta, gamma_,
          t, K1A[t], K1B[t], K2A[t], K2B[t]);
    }
  } else {
    float* e_inf = (float*)d_ws;  // EE floats
    for (int t = 0; t < TS; ++t) {
      const float* Ht = H + (size_t)t * EE * NN;
      k_edge_dense<<<EE, 256, 0, stream>>>(Ht, out + S_OFF + (size_t)t * ROW, e_inf);
      k_node_dense<<<(NN + 255) / 256, 256, 0, stream>>>(
          out, Ht, e_inf, beta, gamma_, t, K1A[t], K1B[t], K2A[t], K2B[t]);
    }
  }
}

// Round 2
// 2031.045 us; speedup vs baseline: 1.0720x; 1.0720x over previous
//
#include <hip/hip_runtime.h>
#include <stdint.h>

// JAX jax_threefry_partitionable=True semantics (verified exact in round 1: absmax 0.0).
constexpr int NN = 10000;          // nodes
constexpr int EE = 1000;           // hyperedges
constexpr int TT = 30;             // output rows
constexpr int TS = TT - 1;         // simulated steps
constexpr int ROW = NN * 3;        // floats per output row
constexpr int S_OFF = TT * ROW;    // state section offset in d_out
constexpr int CAP_E = 48;          // max nodes per edge (Binom(10000,0.001): P(>=48) ~ 1e-30)
constexpr int CAP_N = 16;          // max edges per node (Binom(1000,0.001):  P(>=16) ~ 1e-14)
constexpr int SIM_BLOCKS = 40;     // <= 256 CUs -> all co-resident (manual grid barrier is safe)
constexpr int SIM_THREADS = 256;

// ---- Threefry-2x32, 20 rounds (exact JAX semantics), host+device ----
__host__ __device__ inline void tf2x32(uint32_t k0, uint32_t k1,
                                       uint32_t x0, uint32_t x1,
                                       uint32_t &o0, uint32_t &o1) {
  uint32_t ks2 = k0 ^ k1 ^ 0x1BD11BDAu;
  x0 += k0; x1 += k1;
#define TFR(r) do { x0 += x1; x1 = (x1 << (r)) | (x1 >> (32 - (r))); x1 ^= x0; } while (0)
  TFR(13); TFR(15); TFR(26); TFR(6);
  x0 += k1;  x1 += ks2 + 1u;
  TFR(17); TFR(29); TFR(16); TFR(24);
  x0 += ks2; x1 += k0 + 2u;
  TFR(13); TFR(15); TFR(26); TFR(6);
  x0 += k0;  x1 += k1 + 3u;
  TFR(17); TFR(29); TFR(16); TFR(24);
  x0 += k1;  x1 += ks2 + 4u;
  TFR(13); TFR(15); TFR(26); TFR(6);
  x0 += ks2; x1 += k0 + 5u;
#undef TFR
  o0 = x0; o1 = x1;
}

__device__ inline float bits_to_uniform(uint32_t bits) {
  float f = __uint_as_float((bits >> 9) | 0x3F800000u) - 1.0f;
  return f < 0.f ? 0.f : f;
}

struct StepKeys {           // 464 B, passed by value in kernarg space
  uint32_t k1a[TS], k1b[TS], k2a[TS], k2b[TS];
};

// Exact rounding order as reference (no FMA contraction).
__device__ inline void sir_update(int n, float nv,
                                  const float* __restrict__ pp, const float* __restrict__ sp,
                                  float* __restrict__ po, float* __restrict__ so,
                                  const float* __restrict__ beta, const float* __restrict__ gamma_,
                                  uint32_t k1a, uint32_t k1b, uint32_t k2a, uint32_t k2b) {
  float s0 = sp[n * 3 + 0], s1 = sp[n * 3 + 1];
  float pp0 = pp[n * 3 + 0], pp1 = pp[n * 3 + 1], pp2 = pp[n * 3 + 2];
  float new_cases = __fmul_rn(beta[n], nv);
  float new_rec   = __fmul_rn(gamma_[n], s1);
  float p0 = fminf(1.f, fmaxf(0.f, __fsub_rn(pp0, new_cases)));
  float p1 = fminf(1.f, fmaxf(0.f, __fsub_rn(__fadd_rn(pp1, new_cases), new_rec)));
  float p2 = fminf(1.f, fmaxf(0.f, __fadd_rn(pp2, new_rec)));

  uint32_t a, b;
  tf2x32(k1a, k1b, 0u, (uint32_t)n, a, b); uint32_t bits1 = a ^ b;
  tf2x32(k2a, k2b, 0u, (uint32_t)n, a, b); uint32_t bits2 = a ^ b;
  float u1 = bits_to_uniform(bits1);
  float u2 = bits_to_uniform(bits2);

  bool was_S  = (s0 == 1.f);
  bool was_I  = (s1 == 1.f);
  bool s_to_I = was_S && (u1 < p1);
  bool i_event = was_I && (u1 < p2);
  bool u2lt   = (u2 < 0.5f);
  bool i_to_R = i_event && u2lt;
  bool i_to_S = i_event && !u2lt;
  bool new_S = (was_S && !s_to_I) || i_to_S;
  bool new_I = s_to_I || (was_I && !i_event);
  bool new_R = (!was_S && !was_I) || i_to_R;

  po[n * 3 + 0] = p0; po[n * 3 + 1] = p1; po[n * 3 + 2] = p2;
  so[n * 3 + 0] = new_S ? 1.f : 0.f;
  so[n * 3 + 1] = new_I ? 1.f : 0.f;
  so[n * 3 + 2] = new_R ? 1.f : 0.f;
}

// ---- preprocessing: edge->node lists for all (t,e) rows; zeroes node_cnt ----
__global__ void k_scan(const float* __restrict__ H, int* __restrict__ edge_cnt,
                       uint16_t* __restrict__ edge_nodes, int* __restrict__ node_cnt) {
  const int row = blockIdx.x;  // t*EE + e
  __shared__ int cnt;
  __shared__ uint16_t list[CAP_E];
  if (threadIdx.x == 0) cnt = 0;
  if (threadIdx.x < 10) node_cnt[row * 10 + threadIdx.x] = 0;  // EE*10 == NN: exact cover
  __syncthreads();
  const float4* hrow = reinterpret_cast<const float4*>(H + (size_t)row * NN);
  for (int i = threadIdx.x; i < NN / 4; i += blockDim.x) {
    float4 v = hrow[i];
    int b4 = i * 4;
    if (v.x != 0.f) { int p = atomicAdd(&cnt, 1); if (p < CAP_E) list[p] = (uint16_t)(b4 + 0); }
    if (v.y != 0.f) { int p = atomicAdd(&cnt, 1); if (p < CAP_E) list[p] = (uint16_t)(b4 + 1); }
    if (v.z != 0.f) { int p = atomicAdd(&cnt, 1); if (p < CAP_E) list[p] = (uint16_t)(b4 + 2); }
    if (v.w != 0.f) { int p = atomicAdd(&cnt, 1); if (p < CAP_E) list[p] = (uint16_t)(b4 + 3); }
  }
  __syncthreads();
  int c = cnt < CAP_E ? cnt : CAP_E;
  if (threadIdx.x == 0) edge_cnt[row] = c;
  if ((int)threadIdx.x < c) edge_nodes[(size_t)row * CAP_E + threadIdx.x] = list[threadIdx.x];
}

// ---- preprocessing: transpose into node->edge lists via atomics ----
__global__ void k_scatter(const int* __restrict__ edge_cnt, const uint16_t* __restrict__ edge_nodes,
                          int* __restrict__ node_cnt, uint16_t* __restrict__ node_edges) {
  const int row = blockIdx.x;  // t*EE + e
  const int t = row / EE;
  const int e = row - t * EE;
  const int c = edge_cnt[row];
  for (int i = threadIdx.x; i < c; i += blockDim.x) {
    int m = edge_nodes[(size_t)row * CAP_E + i];
    int slot = atomicAdd(&node_cnt[t * NN + m], 1);
    if (slot < CAP_N) node_edges[((size_t)t * NN + m) * CAP_N + slot] = (uint16_t)e;
  }
}

// copy x into row 0 of both outputs; zero barrier state
__global__ void k_init(const float* __restrict__ x, float* __restrict__ out,
                       unsigned* __restrict__ bar) {
  int i = blockIdx.x * blockDim.x + threadIdx.x;
  if (i < ROW) { out[i] = x[i]; out[S_OFF + i] = x[i]; }
  if (blockIdx.x == 0 && threadIdx.x < 2) bar[threadIdx.x] = 0u;
}

// device-scope sense-reversal grid barrier (all SIM_BLOCKS co-resident)
__device__ inline void gbar(unsigned* bar, unsigned& lgen) {
  __syncthreads();
  if (threadIdx.x == 0) {
    unsigned arrived = __hip_atomic_fetch_add(&bar[0], 1u, __ATOMIC_ACQ_REL,
                                              __HIP_MEMORY_SCOPE_AGENT);
    if (arrived == (unsigned)SIM_BLOCKS - 1u) {
      __hip_atomic_store(&bar[0], 0u, __ATOMIC_RELAXED, __HIP_MEMORY_SCOPE_AGENT);
      __hip_atomic_fetch_add(&bar[1], 1u, __ATOMIC_ACQ_REL, __HIP_MEMORY_SCOPE_AGENT);
    } else {
      while (__hip_atomic_load(&bar[1], __ATOMIC_ACQUIRE, __HIP_MEMORY_SCOPE_AGENT) == lgen) {
        __builtin_amdgcn_s_sleep(8);
      }
    }
  }
  lgen++;
  __syncthreads();
}

// ---- persistent simulation: all 29 steps, edge-centric two-phase ----
__global__ __launch_bounds__(SIM_THREADS)
void k_sim(float* __restrict__ out,
           const int* __restrict__ edge_cnt, const uint16_t* __restrict__ edge_nodes,
           const int* __restrict__ node_cnt, const uint16_t* __restrict__ node_edges,
           const float* __restrict__ beta, const float* __restrict__ gamma_,
           float* __restrict__ e_inf, unsigned* __restrict__ bar, StepKeys keys) {
  __shared__ float lds_e[EE];
  unsigned lgen = 0;
  const int gtid = blockIdx.x * SIM_THREADS + threadIdx.x;

  for (int t = 0; t < TS; ++t) {
    const float* pp = out + (size_t)t * ROW;
    const float* sp = out + S_OFF + (size_t)t * ROW;
    float* po = out + (size_t)(t + 1) * ROW;
    float* so = out + S_OFF + (size_t)(t + 1) * ROW;

    // phase A: per-edge infected sums (exact small-int sums, any order)
    if (gtid < EE) {
      int row = t * EE + gtid;
      int ec = edge_cnt[row];
      const uint16_t* elst = edge_nodes + (size_t)row * CAP_E;
      float s = 0.f;
      for (int m = 0; m < ec; ++m) s += sp[elst[m] * 3 + 1];
      e_inf[gtid] = s;
    }
    gbar(bar, lgen);

    // phase B: stage e_inf to LDS, then per-node gather + SIR update
    for (int i = threadIdx.x; i < EE; i += SIM_THREADS) lds_e[i] = e_inf[i];
    __syncthreads();
    if (gtid < NN) {
      int nc = node_cnt[t * NN + gtid]; if (nc > CAP_N) nc = CAP_N;
      const uint16_t* nlst = node_edges + ((size_t)t * NN + gtid) * CAP_N;
      float nv = 0.f;
      for (int k = 0; k < nc; ++k) nv += lds_e[nlst[k]];
      sir_update(gtid, nv, pp, sp, po, so, beta, gamma_,
                 keys.k1a[t], keys.k1b[t], keys.k2a[t], keys.k2b[t]);
    }
    gbar(bar, lgen);
  }
}

extern "C" void kernel_launch(void* const* d_in, const int* in_sizes, int n_in,
                              void* d_out, int out_size, void* d_ws, size_t ws_size,
                              hipStream_t stream) {
  const float* x      = (const float*)d_in[0];
  const float* H      = (const float*)d_in[1];
  const float* beta   = (const float*)d_in[2];
  const float* gamma_ = (const float*)d_in[3];
  float* out = (float*)d_out;

  // Host-side key chain: key0 = jax.random.key(42) = (0,42); per step split(key,3)
  // with partitionable semantics: subkey i = threefry(key, (0, i)); carry = subkey 0.
  StepKeys keys;
  uint32_t key0 = 0u, key1 = 42u;
  for (int t = 0; t < TS; ++t) {
    uint32_t a0, b0, a1, b1, a2, b2;
    tf2x32(key0, key1, 0u, 0u, a0, b0);   // new carry key
    tf2x32(key0, key1, 0u, 1u, a1, b1);   // k1
    tf2x32(key0, key1, 0u, 2u, a2, b2);   // k2
    keys.k1a[t] = a1; keys.k1b[t] = b1; keys.k2a[t] = a2; keys.k2b[t] = b2;
    key0 = a0; key1 = b0;
  }

  // workspace layout (ws is ~4.6 GB per harness fill traffic; we use ~14 MB)
  size_t off = 0;
  auto take = [&](size_t bytes) { size_t o = off; off += (bytes + 255) & ~(size_t)255; return o; };
  size_t o_ec = take((size_t)TS * EE * sizeof(int));
  size_t o_en = take((size_t)TS * EE * CAP_E * sizeof(uint16_t));
  size_t o_nc = take((size_t)TS * NN * sizeof(int));
  size_t o_ne = take((size_t)TS * NN * CAP_N * sizeof(uint16_t));
  size_t o_ei = take((size_t)EE * sizeof(float));
  size_t o_bar = take(2 * sizeof(unsigned));

  int*      edge_cnt   = (int*)((char*)d_ws + o_ec);
  uint16_t* edge_nodes = (uint16_t*)((char*)d_ws + o_en);
  int*      node_cnt   = (int*)((char*)d_ws + o_nc);
  uint16_t* node_edges = (uint16_t*)((char*)d_ws + o_ne);
  float*    e_inf      = (float*)((char*)d_ws + o_ei);
  unsigned* bar        = (unsigned*)((char*)d_ws + o_bar);

  k_init<<<(ROW + 255) / 256, 256, 0, stream>>>(x, out, bar);
  k_scan<<<TS * EE, 256, 0, stream>>>(H, edge_cnt, edge_nodes, node_cnt);
  k_scatter<<<TS * EE, 64, 0, stream>>>(edge_cnt, edge_nodes, node_cnt, node_edges);
  k_sim<<<SIM_BLOCKS, SIM_THREADS, 0, stream>>>(out, edge_cnt, edge_nodes,
                                                node_cnt, node_edges, beta, gamma_,
                                                e_inf, bar, keys);
}

// Round 3
// 1822.521 us; speedup vs baseline: 1.1946x; 1.1144x over previous
//
#include <hip/hip_runtime.h>
#include <stdint.h>

// JAX jax_threefry_partitionable=True semantics (verified exact: absmax 0.0 in rounds 1-2).
// Round-3 structure: all threefry hoisted out of the sequential chain; per-step work is
// two micro-kernels (edge sums, node update). Grid barriers removed entirely — on MI355X
// device-scope acq/rel forces per-XCD L2 writeback/invalidate (~10-15us each), which made
// the round-2 persistent kernel as slow as the redundant round-1 version.
constexpr int NN = 10000;          // nodes
constexpr int EE = 1000;           // hyperedges
constexpr int TT = 30;             // output rows
constexpr int TS = TT - 1;         // simulated steps
constexpr int ROW = NN * 3;        // floats per output row
constexpr int S_OFF = TT * ROW;    // state section offset in d_out
constexpr int CAP_E = 48;          // max nodes per edge (P(>=48) ~ 1e-30)
constexpr int CAP_N = 16;          // max edges per node (P(>=16) ~ 1e-14)

// ---- Threefry-2x32, 20 rounds (exact JAX semantics), host+device ----
__host__ __device__ inline void tf2x32(uint32_t k0, uint32_t k1,
                                       uint32_t x0, uint32_t x1,
                                       uint32_t &o0, uint32_t &o1) {
  uint32_t ks2 = k0 ^ k1 ^ 0x1BD11BDAu;
  x0 += k0; x1 += k1;
#define TFR(r) do { x0 += x1; x1 = (x1 << (r)) | (x1 >> (32 - (r))); x1 ^= x0; } while (0)
  TFR(13); TFR(15); TFR(26); TFR(6);
  x0 += k1;  x1 += ks2 + 1u;
  TFR(17); TFR(29); TFR(16); TFR(24);
  x0 += ks2; x1 += k0 + 2u;
  TFR(13); TFR(15); TFR(26); TFR(6);
  x0 += k0;  x1 += k1 + 3u;
  TFR(17); TFR(29); TFR(16); TFR(24);
  x0 += k1;  x1 += ks2 + 4u;
  TFR(13); TFR(15); TFR(26); TFR(6);
  x0 += ks2; x1 += k0 + 5u;
#undef TFR
  o0 = x0; o1 = x1;
}

__device__ inline float bits_to_uniform(uint32_t bits) {
  float f = __uint_as_float((bits >> 9) | 0x3F800000u) - 1.0f;
  return f < 0.f ? 0.f : f;
}

struct StepKeys {  // 464 B by value in kernarg space
  uint32_t k1a[TS], k1b[TS], k2a[TS], k2b[TS];
};

// copy x into row 0 of both outputs; zero node_cnt; build compact infected[0]
__global__ void k_init(const float* __restrict__ x, float* __restrict__ out,
                       int* __restrict__ node_cnt, float* __restrict__ inf0) {
  int i = blockIdx.x * blockDim.x + threadIdx.x;
  if (i < ROW) { out[i] = x[i]; out[S_OFF + i] = x[i]; }
  if (i < TS * NN) node_cnt[i] = 0;
  if (i < NN) inf0[i] = x[i * 3 + 1];
}

// precompute ALL uniforms (independent of state): u1[t][n], u2[t][n]
__global__ void k_rand(float* __restrict__ u1, float* __restrict__ u2, StepKeys keys) {
  int t = blockIdx.y;
  int n = blockIdx.x * blockDim.x + threadIdx.x;
  if (n >= NN) return;
  uint32_t a, b;
  tf2x32(keys.k1a[t], keys.k1b[t], 0u, (uint32_t)n, a, b);
  u1[t * NN + n] = bits_to_uniform(a ^ b);
  tf2x32(keys.k2a[t], keys.k2b[t], 0u, (uint32_t)n, a, b);
  u2[t * NN + n] = bits_to_uniform(a ^ b);
}

// edge->node lists for all (t,e) rows + in-place scatter to node->edge lists
__global__ void k_scan(const float* __restrict__ H, int* __restrict__ edge_cnt,
                       uint16_t* __restrict__ edge_nodes, int* __restrict__ node_cnt,
                       uint16_t* __restrict__ node_edges) {
  const int row = blockIdx.x;  // t*EE + e
  const int t = row / EE;
  const int e = row - t * EE;
  __shared__ int cnt;
  __shared__ uint16_t list[CAP_E];
  if (threadIdx.x == 0) cnt = 0;
  __syncthreads();
  const float4* hrow = reinterpret_cast<const float4*>(H + (size_t)row * NN);
  for (int i = threadIdx.x; i < NN / 4; i += blockDim.x) {
    float4 v = hrow[i];
    int b4 = i * 4;
    if (v.x != 0.f) { int p = atomicAdd(&cnt, 1); if (p < CAP_E) list[p] = (uint16_t)(b4 + 0); }
    if (v.y != 0.f) { int p = atomicAdd(&cnt, 1); if (p < CAP_E) list[p] = (uint16_t)(b4 + 1); }
    if (v.z != 0.f) { int p = atomicAdd(&cnt, 1); if (p < CAP_E) list[p] = (uint16_t)(b4 + 2); }
    if (v.w != 0.f) { int p = atomicAdd(&cnt, 1); if (p < CAP_E) list[p] = (uint16_t)(b4 + 3); }
  }
  __syncthreads();
  int c = cnt < CAP_E ? cnt : CAP_E;
  if (threadIdx.x == 0) edge_cnt[row] = c;
  if ((int)threadIdx.x < c) {            // c <= 48 < blockDim: single pass
    uint16_t m = list[threadIdx.x];
    edge_nodes[(size_t)row * CAP_E + threadIdx.x] = m;
    int slot = atomicAdd(&node_cnt[t * NN + m], 1);   // device-scope, coherent
    if (slot < CAP_N) node_edges[((size_t)t * NN + m) * CAP_N + slot] = (uint16_t)e;
  }
}

// per-step phase A: e_inf[e] = sum of infected over edge members (exact small ints)
__global__ void k_edge(const int* __restrict__ edge_cnt, const uint16_t* __restrict__ edge_nodes,
                       const float* __restrict__ inf, float* __restrict__ e_inf, int t) {
  int e = blockIdx.x * blockDim.x + threadIdx.x;
  if (e >= EE) return;
  int row = t * EE + e;
  int ec = edge_cnt[row];
  const uint16_t* el = edge_nodes + (size_t)row * CAP_E;
  float s = 0.f;
  for (int m = 0; m < ec; ++m) s += inf[el[m]];
  e_inf[e] = s;
}

// per-step phase B: node gather + SIR update (exact rounding order, no FMA contraction)
__global__ void k_node(float* __restrict__ out,
                       const int* __restrict__ node_cnt, const uint16_t* __restrict__ node_edges,
                       const float* __restrict__ e_inf,
                       const float* __restrict__ u1t, const float* __restrict__ u2t,
                       const float* __restrict__ beta, const float* __restrict__ gamma_,
                       float* __restrict__ inf_next, int t) {
  int n = blockIdx.x * blockDim.x + threadIdx.x;
  if (n >= NN) return;
  const float* pp = out + (size_t)t * ROW;
  const float* sp = out + S_OFF + (size_t)t * ROW;
  float* po = out + (size_t)(t + 1) * ROW;
  float* so = out + S_OFF + (size_t)(t + 1) * ROW;

  int nc = node_cnt[t * NN + n]; if (nc > CAP_N) nc = CAP_N;
  const uint16_t* nl = node_edges + ((size_t)t * NN + n) * CAP_N;
  float nv = 0.f;
  for (int k = 0; k < nc; ++k) nv += e_inf[nl[k]];  // e_inf is 4 KB -> L1-resident

  float s0 = sp[n * 3 + 0], s1 = sp[n * 3 + 1];
  float pp0 = pp[n * 3 + 0], pp1 = pp[n * 3 + 1], pp2 = pp[n * 3 + 2];
  float new_cases = __fmul_rn(beta[n], nv);
  float new_rec   = __fmul_rn(gamma_[n], s1);
  float p0 = fminf(1.f, fmaxf(0.f, __fsub_rn(pp0, new_cases)));
  float p1 = fminf(1.f, fmaxf(0.f, __fsub_rn(__fadd_rn(pp1, new_cases), new_rec)));
  float p2 = fminf(1.f, fmaxf(0.f, __fadd_rn(pp2, new_rec)));

  float u1 = u1t[n];
  float u2 = u2t[n];
  bool was_S  = (s0 == 1.f);
  bool was_I  = (s1 == 1.f);
  bool s_to_I = was_S && (u1 < p1);
  bool i_event = was_I && (u1 < p2);
  bool u2lt   = (u2 < 0.5f);
  bool i_to_R = i_event && u2lt;
  bool i_to_S = i_event && !u2lt;
  bool new_S = (was_S && !s_to_I) || i_to_S;
  bool new_I = s_to_I || (was_I && !i_event);
  bool new_R = (!was_S && !was_I) || i_to_R;

  po[n * 3 + 0] = p0; po[n * 3 + 1] = p1; po[n * 3 + 2] = p2;
  so[n * 3 + 0] = new_S ? 1.f : 0.f;
  so[n * 3 + 1] = new_I ? 1.f : 0.f;
  so[n * 3 + 2] = new_R ? 1.f : 0.f;
  inf_next[n] = new_I ? 1.f : 0.f;   // compact infected array for next step's k_edge
}

extern "C" void kernel_launch(void* const* d_in, const int* in_sizes, int n_in,
                              void* d_out, int out_size, void* d_ws, size_t ws_size,
                              hipStream_t stream) {
  const float* x      = (const float*)d_in[0];
  const float* H      = (const float*)d_in[1];
  const float* beta   = (const float*)d_in[2];
  const float* gamma_ = (const float*)d_in[3];
  float* out = (float*)d_out;

  // key chain: key0 = jax.random.key(42) = (0,42); per step split(key,3), partitionable:
  // subkey i = threefry(key, (0,i)); carry = subkey 0.
  StepKeys keys;
  uint32_t key0 = 0u, key1 = 42u;
  for (int t = 0; t < TS; ++t) {
    uint32_t a0, b0, a1, b1, a2, b2;
    tf2x32(key0, key1, 0u, 0u, a0, b0);
    tf2x32(key0, key1, 0u, 1u, a1, b1);
    tf2x32(key0, key1, 0u, 2u, a2, b2);
    keys.k1a[t] = a1; keys.k1b[t] = b1; keys.k2a[t] = a2; keys.k2b[t] = b2;
    key0 = a0; key1 = b0;
  }

  // workspace layout (~17 MB of the ws)
  size_t off = 0;
  auto take = [&](size_t bytes) { size_t o = off; off += (bytes + 255) & ~(size_t)255; return o; };
  size_t o_ec = take((size_t)TS * EE * sizeof(int));
  size_t o_en = take((size_t)TS * EE * CAP_E * sizeof(uint16_t));
  size_t o_nc = take((size_t)TS * NN * sizeof(int));
  size_t o_ne = take((size_t)TS * NN * CAP_N * sizeof(uint16_t));
  size_t o_ei = take((size_t)EE * sizeof(float));
  size_t o_if = take((size_t)TT * NN * sizeof(float));
  size_t o_u1 = take((size_t)TS * NN * sizeof(float));
  size_t o_u2 = take((size_t)TS * NN * sizeof(float));

  int*      edge_cnt   = (int*)((char*)d_ws + o_ec);
  uint16_t* edge_nodes = (uint16_t*)((char*)d_ws + o_en);
  int*      node_cnt   = (int*)((char*)d_ws + o_nc);
  uint16_t* node_edges = (uint16_t*)((char*)d_ws + o_ne);
  float*    e_inf      = (float*)((char*)d_ws + o_ei);
  float*    inf        = (float*)((char*)d_ws + o_if);
  float*    u1         = (float*)((char*)d_ws + o_u1);
  float*    u2         = (float*)((char*)d_ws + o_u2);

  k_init<<<(TS * NN + 255) / 256, 256, 0, stream>>>(x, out, node_cnt, inf);
  k_rand<<<dim3((NN + 255) / 256, TS), 256, 0, stream>>>(u1, u2, keys);
  k_scan<<<TS * EE, 256, 0, stream>>>(H, edge_cnt, edge_nodes, node_cnt, node_edges);
  for (int t = 0; t < TS; ++t) {
    k_edge<<<(EE + 255) / 256, 256, 0, stream>>>(edge_cnt, edge_nodes,
                                                 inf + (size_t)t * NN, e_inf, t);
    k_node<<<(NN + 255) / 256, 256, 0, stream>>>(out, node_cnt, node_edges, e_inf,
                                                 u1 + (size_t)t * NN, u2 + (size_t)t * NN,
                                                 beta, gamma_, inf + (size_t)(t + 1) * NN, t);
  }
}

// Round 4
// 1797.829 us; speedup vs baseline: 1.2111x; 1.0137x over previous
//
#include <hip/hip_runtime.h>
#include <stdint.h>

// JAX jax_threefry_partitionable=True semantics (verified exact: absmax 0.0, rounds 1-3).
// Round-4 structure: ALL 29 steps in ONE single-workgroup kernel (1024 thr = 16 waves on
// one CU); cross-step state (p, s) lives in registers/LDS; per-step node values built by
// LDS integer-atomic scatter from edges (exact: sums of small ints). This removes the 58
// per-step launches (~3.6us each) that dominated the controllable time in round 3.
constexpr int NN = 10000;          // nodes
constexpr int EE = 1000;           // hyperedges
constexpr int TT = 30;             // output rows
constexpr int TS = TT - 1;         // simulated steps
constexpr int ROW = NN * 3;        // floats per output row
constexpr int S_OFF = TT * ROW;    // state section offset in d_out
constexpr int CAP_E = 48;          // max nodes per edge (P(>=48) ~ 1e-30)
constexpr int SIMT = 1024;         // sim block size (16 waves)
constexpr int NPT  = 10;           // nodes per thread (1024*10 >= 10000)

// ---- Threefry-2x32, 20 rounds (exact JAX semantics), host+device ----
__host__ __device__ inline void tf2x32(uint32_t k0, uint32_t k1,
                                       uint32_t x0, uint32_t x1,
                                       uint32_t &o0, uint32_t &o1) {
  uint32_t ks2 = k0 ^ k1 ^ 0x1BD11BDAu;
  x0 += k0; x1 += k1;
#define TFR(r) do { x0 += x1; x1 = (x1 << (r)) | (x1 >> (32 - (r))); x1 ^= x0; } while (0)
  TFR(13); TFR(15); TFR(26); TFR(6);
  x0 += k1;  x1 += ks2 + 1u;
  TFR(17); TFR(29); TFR(16); TFR(24);
  x0 += ks2; x1 += k0 + 2u;
  TFR(13); TFR(15); TFR(26); TFR(6);
  x0 += k0;  x1 += k1 + 3u;
  TFR(17); TFR(29); TFR(16); TFR(24);
  x0 += k1;  x1 += ks2 + 4u;
  TFR(13); TFR(15); TFR(26); TFR(6);
  x0 += ks2; x1 += k0 + 5u;
#undef TFR
  o0 = x0; o1 = x1;
}

__device__ inline float bits_to_uniform(uint32_t bits) {
  float f = __uint_as_float((bits >> 9) | 0x3F800000u) - 1.0f;
  return f < 0.f ? 0.f : f;
}

struct StepKeys { uint32_t k1a[TS], k1b[TS], k2a[TS], k2b[TS]; };

// copy x into row 0 of both outputs
__global__ void k_init(const float* __restrict__ x, float* __restrict__ out) {
  int i = blockIdx.x * blockDim.x + threadIdx.x;
  if (i < ROW) { out[i] = x[i]; out[S_OFF + i] = x[i]; }
}

// precompute ALL uniforms (state-independent): u1[t][n], u2[t][n]
__global__ void k_rand(float* __restrict__ u1, float* __restrict__ u2, StepKeys keys) {
  int t = blockIdx.y;
  int n = blockIdx.x * blockDim.x + threadIdx.x;
  if (n >= NN) return;
  uint32_t a, b;
  tf2x32(keys.k1a[t], keys.k1b[t], 0u, (uint32_t)n, a, b);
  u1[t * NN + n] = bits_to_uniform(a ^ b);
  tf2x32(keys.k2a[t], keys.k2b[t], 0u, (uint32_t)n, a, b);
  u2[t * NN + n] = bits_to_uniform(a ^ b);
}

// edge->node lists, stored TRANSPOSED: edge_nodes[(t*CAP_E + m)*EE + e] = m-th member of e
__global__ void k_scan(const float* __restrict__ H, int* __restrict__ edge_cnt,
                       uint16_t* __restrict__ edge_nodes) {
  const int row = blockIdx.x;  // t*EE + e
  const int t = row / EE;
  const int e = row - t * EE;
  __shared__ int cnt;
  __shared__ uint16_t list[CAP_E];
  if (threadIdx.x == 0) cnt = 0;
  __syncthreads();
  const float4* hrow = reinterpret_cast<const float4*>(H + (size_t)row * NN);
  for (int i = threadIdx.x; i < NN / 4; i += blockDim.x) {
    float4 v = hrow[i];
    int b4 = i * 4;
    if (v.x != 0.f) { int p = atomicAdd(&cnt, 1); if (p < CAP_E) list[p] = (uint16_t)(b4 + 0); }
    if (v.y != 0.f) { int p = atomicAdd(&cnt, 1); if (p < CAP_E) list[p] = (uint16_t)(b4 + 1); }
    if (v.z != 0.f) { int p = atomicAdd(&cnt, 1); if (p < CAP_E) list[p] = (uint16_t)(b4 + 2); }
    if (v.w != 0.f) { int p = atomicAdd(&cnt, 1); if (p < CAP_E) list[p] = (uint16_t)(b4 + 3); }
  }
  __syncthreads();
  int c = cnt < CAP_E ? cnt : CAP_E;
  if (threadIdx.x == 0) edge_cnt[row] = c;
  if ((int)threadIdx.x < c)
    edge_nodes[((size_t)t * CAP_E + threadIdx.x) * EE + e] = list[threadIdx.x];
}

// ---- all 29 steps, one workgroup; p in regs, s in LDS, nv via LDS int atomics ----
__global__ __launch_bounds__(SIMT, 4)
void k_sim(float* __restrict__ out, const float* __restrict__ x,
           const int* __restrict__ edge_cnt, const uint16_t* __restrict__ edge_nodes,
           const float* __restrict__ u1, const float* __restrict__ u2,
           const float* __restrict__ beta, const float* __restrict__ gamma_) {
  __shared__ uint8_t s_st[NN];   // 10 KB: state code 0=S 1=I 2=R (one-hot invariant holds)
  __shared__ int nv[NN];         // 40 KB: per-node two-hop infected count (exact ints)
  const int tid = threadIdx.x;

  float p0[NPT], p1[NPT], p2[NPT], bet[NPT], gam[NPT];
#pragma unroll
  for (int k = 0; k < NPT; ++k) {
    int n = tid + k * SIMT;
    if (n < NN) {
      float x0 = x[n * 3 + 0], x1 = x[n * 3 + 1], x2 = x[n * 3 + 2];
      p0[k] = x0; p1[k] = x1; p2[k] = x2;
      s_st[n] = (x1 == 1.f) ? 1 : ((x0 == 1.f) ? 0 : 2);
      bet[k] = beta[n]; gam[k] = gamma_[n];
    }
  }
  __syncthreads();

  for (int t = 0; t < TS; ++t) {
    // zero nv
#pragma unroll
    for (int k = 0; k < NPT; ++k) { int n = tid + k * SIMT; if (n < NN) nv[n] = 0; }
    __syncthreads();

    // edge phase: s_e = #infected members; scatter s_e into every member's nv
    if (tid < EE) {
      int row = t * EE + tid;
      int ec = edge_cnt[row];
      const uint16_t* base = edge_nodes + (size_t)t * CAP_E * EE + tid;
      int s = 0;
      for (int m = 0; m < ec; ++m) s += (s_st[base[(size_t)m * EE]] == 1) ? 1 : 0;
      for (int m = 0; m < ec; ++m) atomicAdd(&nv[base[(size_t)m * EE]], s);
    }
    __syncthreads();

    // node phase (exact rounding order; no FMA contraction)
    float* po = out + (size_t)(t + 1) * ROW;
    float* so = out + S_OFF + (size_t)(t + 1) * ROW;
    const float* u1t = u1 + (size_t)t * NN;
    const float* u2t = u2 + (size_t)t * NN;
#pragma unroll
    for (int k = 0; k < NPT; ++k) {
      int n = tid + k * SIMT;
      if (n < NN) {
        int st = s_st[n];
        float s1 = (st == 1) ? 1.f : 0.f;
        float new_cases = __fmul_rn(bet[k], (float)nv[n]);
        float new_rec   = __fmul_rn(gam[k], s1);
        float q0 = fminf(1.f, fmaxf(0.f, __fsub_rn(p0[k], new_cases)));
        float q1 = fminf(1.f, fmaxf(0.f, __fsub_rn(__fadd_rn(p1[k], new_cases), new_rec)));
        float q2 = fminf(1.f, fmaxf(0.f, __fadd_rn(p2[k], new_rec)));
        p0[k] = q0; p1[k] = q1; p2[k] = q2;

        float uu1 = u1t[n], uu2 = u2t[n];
        bool was_S  = (st == 0);
        bool was_I  = (st == 1);
        bool s_to_I = was_S && (uu1 < q1);
        bool i_event = was_I && (uu1 < q2);
        bool u2lt   = (uu2 < 0.5f);
        bool i_to_R = i_event && u2lt;
        bool i_to_S = i_event && !u2lt;
        bool new_S = (was_S && !s_to_I) || i_to_S;
        bool new_I = s_to_I || (was_I && !i_event);
        bool new_R = (!was_S && !was_I) || i_to_R;

        po[n * 3 + 0] = q0; po[n * 3 + 1] = q1; po[n * 3 + 2] = q2;
        so[n * 3 + 0] = new_S ? 1.f : 0.f;
        so[n * 3 + 1] = new_I ? 1.f : 0.f;
        so[n * 3 + 2] = new_R ? 1.f : 0.f;
        s_st[n] = new_I ? 1 : (new_S ? 0 : 2);
      }
    }
    __syncthreads();  // protect s_st / nv before next iteration's zero+edge phase
  }
}

extern "C" void kernel_launch(void* const* d_in, const int* in_sizes, int n_in,
                              void* d_out, int out_size, void* d_ws, size_t ws_size,
                              hipStream_t stream) {
  const float* x      = (const float*)d_in[0];
  const float* H      = (const float*)d_in[1];
  const float* beta   = (const float*)d_in[2];
  const float* gamma_ = (const float*)d_in[3];
  float* out = (float*)d_out;

  // key chain: key0 = jax.random.key(42) = (0,42); split(key,3) partitionable:
  // subkey i = threefry(key, (0,i)); carry = subkey 0.
  StepKeys keys;
  uint32_t key0 = 0u, key1 = 42u;
  for (int t = 0; t < TS; ++t) {
    uint32_t a0, b0, a1, b1, a2, b2;
    tf2x32(key0, key1, 0u, 0u, a0, b0);
    tf2x32(key0, key1, 0u, 1u, a1, b1);
    tf2x32(key0, key1, 0u, 2u, a2, b2);
    keys.k1a[t] = a1; keys.k1b[t] = b1; keys.k2a[t] = a2; keys.k2b[t] = b2;
    key0 = a0; key1 = b0;
  }

  // workspace layout (~5.2 MB)
  size_t off = 0;
  auto take = [&](size_t bytes) { size_t o = off; off += (bytes + 255) & ~(size_t)255; return o; };
  size_t o_ec = take((size_t)TS * EE * sizeof(int));
  size_t o_en = take((size_t)TS * EE * CAP_E * sizeof(uint16_t));
  size_t o_u1 = take((size_t)TS * NN * sizeof(float));
  size_t o_u2 = take((size_t)TS * NN * sizeof(float));

  int*      edge_cnt   = (int*)((char*)d_ws + o_ec);
  uint16_t* edge_nodes = (uint16_t*)((char*)d_ws + o_en);
  float*    u1         = (float*)((char*)d_ws + o_u1);
  float*    u2         = (float*)((char*)d_ws + o_u2);

  k_init<<<(ROW + 255) / 256, 256, 0, stream>>>(x, out);
  k_rand<<<dim3((NN + 255) / 256, TS), 256, 0, stream>>>(u1, u2, keys);
  k_scan<<<TS * EE, 256, 0, stream>>>(H, edge_cnt, edge_nodes);
  k_sim<<<1, SIMT, 0, stream>>>(out, x, edge_cnt, edge_nodes, u1, u2, beta, gamma_);
}